// Round 8
// baseline (119.870 us; speedup 1.0000x reference)
//
#include <hip/hip_runtime.h>
#include <hip/hip_bf16.h>
#include <cfloat>
#include <math.h>

#define BB 4
#define NR 180
#define CC 512
#define HH 48
#define WW 48
#define FF (CC*4)      // 2048
#define OO 64
#define EPSV 1e-5f

// ---- ws layout (bytes) ----
// featB  : BB*HW*CC u16        = 9,437,184   (mapped u16 domain)
// W1T4   : [512][64][4] f32    =   524,288
// pp     : [b*NR+n][2048] u16  = 2,949,120   (mapped, ReLU'd)
// colmax : [b*NR+n][48][2][512] u16 = 70,778,880 (mapped; only in-span rows written)
//
// order-preserving map bf16 -> u16: neg ? ~u : u|0x8000; max/ReLU = v_pk_max_u16.

typedef unsigned short us2 __attribute__((ext_vector_type(2)));

__device__ __forceinline__ unsigned pmax(unsigned a, unsigned b) {
    return __builtin_bit_cast(unsigned, __builtin_elementwise_max(
        __builtin_bit_cast(us2, a), __builtin_bit_cast(us2, b)));
}
__device__ __forceinline__ uint4 pmax4(uint4 a, uint4 b) {
    return make_uint4(pmax(a.x,b.x), pmax(a.y,b.y), pmax(a.z,b.z), pmax(a.w,b.w));
}
__device__ __forceinline__ unsigned mapb(float f) {
    unsigned fu = __float_as_uint(f);
    unsigned u = fu >> 16;
    return (fu >> 31) ? (~u & 0xFFFFu) : (u | 0x8000u);
}
__device__ __forceinline__ void unmap2(unsigned m, float& lo, float& hi) {
    unsigned t = ((~m) >> 15) & 0x00010001u;
    unsigned u = m ^ (0x80008000u ^ (t * 0x7FFFu));
    lo = __uint_as_float(u << 16);
    hi = __uint_as_float(u & 0xffff0000u);
}

// ---------------- Kernel 1: transposes --------------------------------------
__global__ __launch_bounds__(256) void k_prep(const float* __restrict__ feat,
                                              const float* __restrict__ W1,
                                              ushort* __restrict__ featB,
                                              float* __restrict__ W1T4) {
    __shared__ float tile[32][33];
    int t = threadIdx.x;
    int L = blockIdx.x;

    if (L < 4608) {
        const int S = HH * WW;                 // 2304
        int b   = L & 3;
        int m   = L >> 2;                      // 0..1151
        int s0  = (m % 72) * 32;
        int c0  = (m / 72) * 32;
        const float* src = feat + (size_t)b * CC * S;
        ushort* dst = featB + (size_t)b * S * CC;

        int cl = t >> 3;
        int sx = (t & 7) << 2;
        float4 v = *(const float4*)(src + (size_t)(c0 + cl) * S + s0 + sx);
        tile[cl][sx] = v.x; tile[cl][sx+1] = v.y; tile[cl][sx+2] = v.z; tile[cl][sx+3] = v.w;
        __syncthreads();

        int sl = t >> 3;
        int c4 = (t & 7) << 2;
        unsigned u0 = mapb(tile[c4][sl])   | (mapb(tile[c4+1][sl]) << 16);
        unsigned u1 = mapb(tile[c4+2][sl]) | (mapb(tile[c4+3][sl]) << 16);
        *(uint2*)(dst + (size_t)(s0 + sl) * CC + c0 + c4) = make_uint2(u0, u1);
    } else {
        int kt = L - 4608;                         // 0..127
        int k0 = (kt >> 1) * 32, o0 = (kt & 1) * 32;
        int tx = t & 31, ty = t >> 5;
        #pragma unroll
        for (int k = 0; k < 4; k++) {
            int row = ty + k * 8;
            tile[row][tx] = W1[(size_t)(o0 + row) * FF + (k0 + tx)];
        }
        __syncthreads();
        #pragma unroll
        for (int k = 0; k < 4; k++) {
            int row = ty + k * 8;
            int kk = k0 + row;
            int o  = o0 + tx;
            W1T4[(size_t)(kk >> 2) * 256 + o * 4 + (kk & 3)] = tile[tx][row];
        }
    }
}

// ---------------- Kernel 2a: per-row column-segment maxes (shared reads) ----
// block = (b,h): stage feature row (48 KB) in LDS once; all ROIs whose span
// contains h compute their 2 column-segment maxes from LDS. 192 blocks x 512.
__global__ __launch_bounds__(512) void k_colmax(const ushort* __restrict__ featB,
                                                const float* __restrict__ rois,
                                                ushort* __restrict__ colmax) {
    __shared__ uint4 row[48 * 64];            // [w][cgroup], 48 KB
    __shared__ int4 meta[NR];                 // r0, r2, r1, (ew0|sw1<<8|wsz<<16)
    int b = blockIdx.x & 3;
    int h = blockIdx.x >> 2;                  // 0..47
    int t = threadIdx.x;

    if (t < NR) {
        float4 r = ((const float4*)(rois))[b * NR + t];
        int r0 = (int)(r.x * 0.25f);
        int r1 = (int)(r.y * 0.25f);
        int r2 = (int)ceilf(r.z * 0.25f);
        int r3 = (int)ceilf(r.w * 0.25f);
        int wsz = r3 - r1 + 1;
        int ew0 = (wsz + 1) >> 1, sw1 = wsz >> 1;
        meta[t] = make_int4(r0, r2, r1, ew0 | (sw1 << 8) | (wsz << 16));
    }
    {
        const uint4* src = (const uint4*)(featB + ((size_t)(b * HH + h) * WW) * CC);
        #pragma unroll
        for (int i = 0; i < 6; i++) row[t + 512 * i] = src[t + 512 * i];
    }
    __syncthreads();

    int wv = t >> 6, lane = t & 63;
    for (int n = wv; n < NR; n += 8) {
        int4 m = meta[n];                     // LDS broadcast, wave-uniform
        if (h < m.x || h > m.y) continue;     // uniform branch
        int r1  = m.z;
        int ew0 = m.w & 255;
        int sw1 = (m.w >> 8) & 255;
        int wsz = m.w >> 16;

        uint4 s0 = make_uint4(0,0,0,0);
        {
            int w = r1, e = r1 + ew0;
            for (; w + 2 <= e; w += 2)
                s0 = pmax4(s0, pmax4(row[w * 64 + lane], row[(w + 1) * 64 + lane]));
            if (w < e) s0 = pmax4(s0, row[w * 64 + lane]);
        }
        uint4 s1 = make_uint4(0,0,0,0);
        {
            int w = r1 + sw1, e = r1 + wsz;
            for (; w + 2 <= e; w += 2)
                s1 = pmax4(s1, pmax4(row[w * 64 + lane], row[(w + 1) * 64 + lane]));
            if (w < e) s1 = pmax4(s1, row[w * 64 + lane]);
        }
        uint4* dst = (uint4*)((unsigned*)(colmax) + ((size_t)(b * NR + n) * 48 + h) * 512);
        dst[lane]      = s0;                  // oj=0
        dst[64 + lane] = s1;                  // oj=1
    }
}

// ---------------- Kernel 2b: row-range reduce -> quadrants + ReLU -----------
// block = (b,n): 720 blocks x 256 (4 rowgroups x 64 cgroups)
__global__ __launch_bounds__(256) void k_rowmax(const ushort* __restrict__ colmax,
                                                const float* __restrict__ rois,
                                                ushort* __restrict__ pp) {
    __shared__ unsigned lu[4][16][64];        // 16 KB
    int b = blockIdx.x & 3;
    int n = blockIdx.x >> 2;
    int tid = threadIdx.x;
    int g = tid >> 6, c = tid & 63;

    const float* roi = rois + ((size_t)b * NR + n) * 4;
    int r0 = (int)(roi[0] * 0.25f);
    int r2 = (int)ceilf(roi[2] * 0.25f);
    int hs  = r2 - r0 + 1;
    int eh0 = (hs + 1) >> 1, sh1 = hs >> 1;

    uint4 q00 = make_uint4(0,0,0,0), q01 = q00, q10 = q00, q11 = q00;
    const unsigned* base = (const unsigned*)(colmax) + ((size_t)(b * NR + n) * 48 + r0) * 512;
    for (int hr = g; hr < hs; hr += 4) {
        const uint4* rw = (const uint4*)(base + (size_t)hr * 512);
        uint4 s0 = rw[c];
        uint4 s1 = rw[64 + c];
        if (hr <  eh0) { q00 = pmax4(q00, s0); q01 = pmax4(q01, s1); }
        if (hr >= sh1) { q10 = pmax4(q10, s0); q11 = pmax4(q11, s1); }
    }

    // repack: lu[g][m*4+{0..3}][c] = {(ch2m,oi0),(ch2m,oi1),(ch2m+1,oi0),(ch2m+1,oi1)}
    {
        unsigned a, b2;
        a = q00.x; b2 = q01.x;
        lu[g][0*4 + 0][c] = (a & 0xFFFFu) | (b2 << 16);
        lu[g][0*4 + 2][c] = (a >> 16)     | (b2 & 0xFFFF0000u);
        a = q10.x; b2 = q11.x;
        lu[g][0*4 + 1][c] = (a & 0xFFFFu) | (b2 << 16);
        lu[g][0*4 + 3][c] = (a >> 16)     | (b2 & 0xFFFF0000u);
        a = q00.y; b2 = q01.y;
        lu[g][1*4 + 0][c] = (a & 0xFFFFu) | (b2 << 16);
        lu[g][1*4 + 2][c] = (a >> 16)     | (b2 & 0xFFFF0000u);
        a = q10.y; b2 = q11.y;
        lu[g][1*4 + 1][c] = (a & 0xFFFFu) | (b2 << 16);
        lu[g][1*4 + 3][c] = (a >> 16)     | (b2 & 0xFFFF0000u);
        a = q00.z; b2 = q01.z;
        lu[g][2*4 + 0][c] = (a & 0xFFFFu) | (b2 << 16);
        lu[g][2*4 + 2][c] = (a >> 16)     | (b2 & 0xFFFF0000u);
        a = q10.z; b2 = q11.z;
        lu[g][2*4 + 1][c] = (a & 0xFFFFu) | (b2 << 16);
        lu[g][2*4 + 3][c] = (a >> 16)     | (b2 & 0xFFFF0000u);
        a = q00.w; b2 = q01.w;
        lu[g][3*4 + 0][c] = (a & 0xFFFFu) | (b2 << 16);
        lu[g][3*4 + 2][c] = (a >> 16)     | (b2 & 0xFFFF0000u);
        a = q10.w; b2 = q11.w;
        lu[g][3*4 + 1][c] = (a & 0xFFFFu) | (b2 << 16);
        lu[g][3*4 + 3][c] = (a >> 16)     | (b2 & 0xFFFF0000u);
    }
    __syncthreads();

    int c2 = tid & 63, j0 = (tid >> 6) * 4;
    unsigned ou[4];
    #pragma unroll
    for (int jj = 0; jj < 4; jj++) {
        int j = j0 + jj;
        unsigned m = pmax(pmax(lu[0][j][c2], lu[1][j][c2]),
                          pmax(lu[2][j][c2], lu[3][j][c2]));
        ou[jj] = pmax(m, 0x80008000u);        // ReLU: mapped(+0)=0x8000
    }
    unsigned* dst = (unsigned*)(pp + (size_t)(b * NR + n) * FF);
    *(uint4*)(dst + c2 * 16 + j0) = make_uint4(ou[0], ou[1], ou[2], ou[3]);
}

// ---------------- Kernel 3: unmap + BN1 + GEMM + BN2 ------------------------
__global__ __launch_bounds__(1024) void k_gemm(const ushort* __restrict__ pp,
                                               const float* __restrict__ W1T4,
                                               const float* __restrict__ bl1,
                                               const float* __restrict__ g1,
                                               const float* __restrict__ b1,
                                               const float* __restrict__ g2,
                                               const float* __restrict__ b2,
                                               float* __restrict__ out) {
    __shared__ float xs[BB][FF];          // 32 KB
    __shared__ float pd[16][BB][OO];      // 16 KB
    __shared__ float pw[16][OO];          // 4 KB
    __shared__ float part_s[16], part_q[16];
    __shared__ float sm2[4], sq2[4];
    int n = blockIdx.x;
    int tid = threadIdx.x;

    float s_acc = 0.f, q_acc = 0.f;
    #pragma unroll
    for (int k2 = 0; k2 < 2; k2++) {
        int gi = tid + (k2 << 10);
        int bb = gi >> 9;
        int idx = gi & 511;
        const uint2* base = (const uint2*)(pp + (size_t)(bb * NR + n) * FF);
        uint2 m = base[idx];
        float v0, v1, v2, v3;
        unmap2(m.x, v0, v1);
        unmap2(m.y, v2, v3);
        *(float4*)&xs[bb][idx << 2] = make_float4(v0, v1, v2, v3);
        s_acc += v0 + v1 + v2 + v3;
        q_acc += v0*v0 + v1*v1 + v2*v2 + v3*v3;
    }
    for (int off = 32; off; off >>= 1) {
        s_acc += __shfl_down(s_acc, off);
        q_acc += __shfl_down(q_acc, off);
    }
    if ((tid & 63) == 0) { part_s[tid >> 6] = s_acc; part_q[tid >> 6] = q_acc; }
    __syncthreads();
    float ts = 0.f, tq = 0.f;
    #pragma unroll
    for (int i = 0; i < 16; i++) { ts += part_s[i]; tq += part_q[i]; }
    const float inv1 = 1.f / (float)(BB * FF);
    float mean = ts * inv1;
    float var  = tq * inv1 - mean * mean;
    float a1n  = g1[n] * rsqrtf(var + EPSV);
    float c1n  = b1[n] - mean * a1n;

    int sc = tid >> 6;
    int o  = tid & 63;
    int k4a = sc << 5;
    float a0 = 0.f, a1 = 0.f, a2 = 0.f, a3 = 0.f, wsum = 0.f;
    #pragma unroll 4
    for (int k4 = k4a; k4 < k4a + 32; k4++) {
        float4 w4 = *(const float4*)(W1T4 + (size_t)k4 * 256 + o * 4);
        float4 x0 = *(const float4*)&xs[0][k4 << 2];
        float4 x1 = *(const float4*)&xs[1][k4 << 2];
        float4 x2 = *(const float4*)&xs[2][k4 << 2];
        float4 x3 = *(const float4*)&xs[3][k4 << 2];
        wsum += w4.x + w4.y + w4.z + w4.w;
        a0 += w4.x*x0.x + w4.y*x0.y + w4.z*x0.z + w4.w*x0.w;
        a1 += w4.x*x1.x + w4.y*x1.y + w4.z*x1.z + w4.w*x1.w;
        a2 += w4.x*x2.x + w4.y*x2.y + w4.z*x2.z + w4.w*x2.w;
        a3 += w4.x*x3.x + w4.y*x3.y + w4.z*x3.z + w4.w*x3.w;
    }
    pd[sc][0][o] = a0; pd[sc][1][o] = a1; pd[sc][2][o] = a2; pd[sc][3][o] = a3;
    pw[sc][o] = wsum;
    __syncthreads();

    float y = 0.f;
    int b = tid >> 6;
    if (tid < 256) {
        float dot = 0.f, wsm = 0.f;
        #pragma unroll
        for (int ss = 0; ss < 16; ss++) { dot += pd[ss][b][o]; wsm += pw[ss][o]; }
        y = a1n * dot + c1n * wsm + bl1[o];
        float rs = y, rq = y * y;
        for (int off = 32; off; off >>= 1) {
            rs += __shfl_down(rs, off);
            rq += __shfl_down(rq, off);
        }
        if (o == 0) { sm2[b] = rs; sq2[b] = rq; }
    }
    __syncthreads();
    if (tid < 256) {
        float sm  = sm2[0] + sm2[1] + sm2[2] + sm2[3];
        float sqm = sq2[0] + sq2[1] + sq2[2] + sq2[3];
        const float inv2 = 1.f / 256.f;
        float mean2 = sm * inv2;
        float var2  = sqm * inv2 - mean2 * mean2;
        float r2s = rsqrtf(var2 + EPSV);
        out[((size_t)b * NR + n) * OO + o] = (y - mean2) * r2s * g2[n] + b2[n];
    }
}

extern "C" void kernel_launch(void* const* d_in, const int* in_sizes, int n_in,
                              void* d_out, int out_size, void* d_ws, size_t ws_size,
                              hipStream_t stream) {
    const float* feat = (const float*)d_in[0];
    const float* rois = (const float*)d_in[1];
    const float* g1   = (const float*)d_in[2];
    const float* b1   = (const float*)d_in[3];
    const float* W1   = (const float*)d_in[4];
    const float* bl1  = (const float*)d_in[5];
    const float* g2   = (const float*)d_in[6];
    const float* b2   = (const float*)d_in[7];
    float* out = (float*)d_out;

    ushort* featB  = (ushort*)d_ws;                           // 9,437,184 B
    float*  W1T4   = (float*)((char*)d_ws + 9437184);         //   524,288 B
    ushort* pp     = (ushort*)((char*)d_ws + 9961472);        // 2,949,120 B
    ushort* colmax = (ushort*)((char*)d_ws + 12910592);       // 70,778,880 B

    k_prep<<<4736, 256, 0, stream>>>(feat, W1, featB, W1T4);
    k_colmax<<<192, 512, 0, stream>>>(featB, rois, colmax);
    k_rowmax<<<720, 256, 0, stream>>>(colmax, rois, pp);
    k_gemm<<<NR, 1024, 0, stream>>>(pp, W1T4, bl1, g1, b1, g2, b2, out);
}

// Round 9
// 119.584 us; speedup vs baseline: 1.0024x; 1.0024x over previous
//
#include <hip/hip_runtime.h>
#include <hip/hip_bf16.h>
#include <cfloat>
#include <math.h>

#define BB 4
#define NR 180
#define CC 512
#define HH 48
#define WW 48
#define FF (CC*4)      // 2048
#define OO 64
#define EPSV 1e-5f

// ---- ws layout (bytes) ----
// W1T4   : [512][64][4] f32         = 524,288
// colmax : [b*NR+n][48][2][256u32]  = 70,778,880 (mapped u16; in-span rows only)
//
// order-preserving map bf16 -> u16: neg ? ~u : u|0x8000; max/ReLU = v_pk_max_u16.
// 2 dispatches total: K1 = colmax-from-original-layout + W1 transpose;
// K2 = rowmax + BN1-folded GEMM + BN2.

typedef unsigned short us2 __attribute__((ext_vector_type(2)));

__device__ __forceinline__ unsigned pmax(unsigned a, unsigned b) {
    return __builtin_bit_cast(unsigned, __builtin_elementwise_max(
        __builtin_bit_cast(us2, a), __builtin_bit_cast(us2, b)));
}
__device__ __forceinline__ uint4 pmax4(uint4 a, uint4 b) {
    return make_uint4(pmax(a.x,b.x), pmax(a.y,b.y), pmax(a.z,b.z), pmax(a.w,b.w));
}
__device__ __forceinline__ ushort mapb(float f) {        // fp32 -> mapped u16 (trunc)
    unsigned fu = __float_as_uint(f);
    unsigned u = fu >> 16;
    return (ushort)((fu >> 31) ? (~u & 0xFFFFu) : (u | 0x8000u));
}
__device__ __forceinline__ void unmap2(unsigned m, float& lo, float& hi) {
    unsigned t = ((~m) >> 15) & 0x00010001u;
    unsigned u = m ^ (0x80008000u ^ (t * 0x7FFFu));
    lo = __uint_as_float(u << 16);
    hi = __uint_as_float(u & 0xffff0000u);
}

// ---------------- Kernel 1: colmax from original layout + W1 transpose ------
// blk < 192 : (b,h). Stage row [w][c] mapped-u16 in LDS (48 KB), then each
//             wave handles ROIs n = wv + 8i whose h-span contains h, computing
//             the 2 column-segment maxes (uint4 = 8 ch per lane).
// blk >= 192: W1 [64,2048] -> W1T4 tile (kt = blk-192, 0..127), 256 threads.
__global__ __launch_bounds__(512) void k_colmax(const float* __restrict__ feat,
                                                const float* __restrict__ rois,
                                                const float* __restrict__ W1,
                                                ushort* __restrict__ colmax,
                                                float* __restrict__ W1T4) {
    __shared__ ushort lrow[48 * 512];         // [w][c], 48 KB
    __shared__ int4 meta[NR];
    __shared__ float tile[32][33];
    const int S = HH * WW;                    // 2304
    int blk = blockIdx.x;
    int t = threadIdx.x;

    if (blk >= 192) {                         // ---- W1 transpose path ----
        int kt = blk - 192;                   // 0..127
        int k0 = (kt >> 1) * 32, o0 = (kt & 1) * 32;
        int tx = t & 31, ty = (t >> 5) & 7;
        bool act = (t < 256);
        if (act) {
            #pragma unroll
            for (int k = 0; k < 4; k++) {
                int row = ty + k * 8;
                tile[row][tx] = W1[(size_t)(o0 + row) * FF + (k0 + tx)];
            }
        }
        __syncthreads();
        if (act) {
            #pragma unroll
            for (int k = 0; k < 4; k++) {
                int row = ty + k * 8;
                int kk = k0 + row;
                int o  = o0 + tx;
                W1T4[(size_t)(kk >> 2) * 256 + o * 4 + (kk & 3)] = tile[tx][row];
            }
        }
        return;
    }

    int b = blk & 3;
    int h = blk >> 2;                         // 0..47

    if (t < NR) {
        float4 r = ((const float4*)(rois))[b * NR + t];
        int r0 = (int)(r.x * 0.25f);
        int r1 = (int)(r.y * 0.25f);
        int r2 = (int)ceilf(r.z * 0.25f);
        int r3 = (int)ceilf(r.w * 0.25f);
        int wsz = r3 - r1 + 1;
        int ew0 = (wsz + 1) >> 1, sw1 = wsz >> 1;
        meta[t] = make_int4(r0, r2, r1, ew0 | (sw1 << 8) | (wsz << 16));
    }
    // stage: 6144 float4s, linear = i*512 + t (coalesced); c = lin/12, w4 = lin%12
    {
        const float* src = feat + (size_t)b * CC * S + h * WW;
        #pragma unroll
        for (int i = 0; i < 12; i++) {
            int lin = i * 512 + t;
            int c = lin / 12, w4 = lin - c * 12;
            float4 v = *(const float4*)(src + (size_t)c * S + (w4 << 2));
            int w = w4 << 2;
            lrow[(w    ) * 512 + c] = mapb(v.x);
            lrow[(w + 1) * 512 + c] = mapb(v.y);
            lrow[(w + 2) * 512 + c] = mapb(v.z);
            lrow[(w + 3) * 512 + c] = mapb(v.w);
        }
    }
    __syncthreads();

    const uint4* row = (const uint4*)lrow;    // row[w*64 + lane] = 8 channels
    int wv = t >> 6, lane = t & 63;
    for (int n = wv; n < NR; n += 8) {
        int4 m = meta[n];                     // wave-uniform
        if (h < m.x || h > m.y) continue;
        int r1  = m.z;
        int ew0 = m.w & 255;
        int sw1 = (m.w >> 8) & 255;
        int wsz = m.w >> 16;

        uint4 s0 = make_uint4(0,0,0,0);
        {
            int w = r1, e = r1 + ew0;
            for (; w + 2 <= e; w += 2)
                s0 = pmax4(s0, pmax4(row[w * 64 + lane], row[(w + 1) * 64 + lane]));
            if (w < e) s0 = pmax4(s0, row[w * 64 + lane]);
        }
        uint4 s1 = make_uint4(0,0,0,0);
        {
            int w = r1 + sw1, e = r1 + wsz;
            for (; w + 2 <= e; w += 2)
                s1 = pmax4(s1, pmax4(row[w * 64 + lane], row[(w + 1) * 64 + lane]));
            if (w < e) s1 = pmax4(s1, row[w * 64 + lane]);
        }
        uint4* dst = (uint4*)((unsigned*)(colmax) + ((size_t)(b * NR + n) * 48 + h) * 512);
        dst[lane]      = s0;                  // oj=0 : uints [0..255]
        dst[64 + lane] = s1;                  // oj=1 : uints [256..511]
    }
}

// ---------------- Kernel 2: rowmax + unmap + BN1 + GEMM + BN2 ---------------
// grid 180 (n), 1024 threads. Phase A: reduce colmax rows of the 4 (b,n) ROIs
// into xs[4][2048] (f = c*4+oi*2+oj) + BN1 stats. Phase B: GEMM + BN2.
__global__ __launch_bounds__(1024) void k_gemm(const ushort* __restrict__ colmax,
                                               const float* __restrict__ rois,
                                               const float* __restrict__ W1T4,
                                               const float* __restrict__ bl1,
                                               const float* __restrict__ g1,
                                               const float* __restrict__ b1,
                                               const float* __restrict__ g2,
                                               const float* __restrict__ b2,
                                               float* __restrict__ out) {
    __shared__ float xs[BB][FF];          // 32 KB
    __shared__ uint4 lds4[4][256];        // 16 KB quadrant partials
    __shared__ float pd[16][BB][OO];      // 16 KB
    __shared__ float pw[16][OO];          // 4 KB
    __shared__ float part_s[16], part_q[16];
    __shared__ float sm2[4], sq2[4];
    int n = blockIdx.x;
    int tid = threadIdx.x;
    int hgrp = tid >> 8;                  // 0..3
    int cu   = tid & 255;                 // channel-pair group (2 ch per uint)

    float s_acc = 0.f, q_acc = 0.f;
    for (int bb = 0; bb < BB; bb++) {
        const float* roi = rois + ((size_t)bb * NR + n) * 4;
        int r0 = (int)(roi[0] * 0.25f);
        int r2 = (int)ceilf(roi[2] * 0.25f);
        int hs  = r2 - r0 + 1;
        int eh0 = (hs + 1) >> 1, sh1 = hs >> 1;

        unsigned q00 = 0, q01 = 0, q10 = 0, q11 = 0;
        const unsigned* base = (const unsigned*)(colmax) + ((size_t)(bb * NR + n) * 48 + r0) * 512;
        for (int hr = hgrp; hr < hs; hr += 4) {
            const unsigned* rowp = base + (size_t)hr * 512;
            unsigned s0 = rowp[cu];
            unsigned s1 = rowp[256 + cu];
            if (hr <  eh0) { q00 = pmax(q00, s0); q01 = pmax(q01, s1); }
            if (hr >= sh1) { q10 = pmax(q10, s0); q11 = pmax(q11, s1); }
        }
        __syncthreads();                  // lds4 free (prev bb's combine done)
        lds4[hgrp][cu] = make_uint4(q00, q01, q10, q11);
        __syncthreads();
        if (tid < 256) {
            uint4 m = pmax4(pmax4(lds4[0][tid], lds4[1][tid]),
                            pmax4(lds4[2][tid], lds4[3][tid]));
            // ReLU in mapped domain
            m.x = pmax(m.x, 0x80008000u); m.y = pmax(m.y, 0x80008000u);
            m.z = pmax(m.z, 0x80008000u); m.w = pmax(m.w, 0x80008000u);
            // unmap: lo = channel 2*tid, hi = channel 2*tid+1; f = c*4+oi*2+oj
            float l00,h00,l01,h01,l10,h10,l11,h11;
            unmap2(m.x, l00, h00);        // (oi0,oj0)
            unmap2(m.y, l01, h01);        // (oi0,oj1)
            unmap2(m.z, l10, h10);        // (oi1,oj0)
            unmap2(m.w, l11, h11);        // (oi1,oj1)
            int f0 = tid << 3;
            *(float4*)&xs[bb][f0]     = make_float4(l00, l01, l10, l11);
            *(float4*)&xs[bb][f0 + 4] = make_float4(h00, h01, h10, h11);
            s_acc += l00 + l01 + l10 + l11 + h00 + h01 + h10 + h11;
            q_acc += l00*l00 + l01*l01 + l10*l10 + l11*l11
                   + h00*h00 + h01*h01 + h10*h10 + h11*h11;
        }
    }

    // BN1 stats reduction (threads >=256 hold 0)
    for (int off = 32; off; off >>= 1) {
        s_acc += __shfl_down(s_acc, off);
        q_acc += __shfl_down(q_acc, off);
    }
    if ((tid & 63) == 0) { part_s[tid >> 6] = s_acc; part_q[tid >> 6] = q_acc; }
    __syncthreads();
    float ts = 0.f, tq = 0.f;
    #pragma unroll
    for (int i = 0; i < 16; i++) { ts += part_s[i]; tq += part_q[i]; }
    const float inv1 = 1.f / (float)(BB * FF);
    float mean = ts * inv1;
    float var  = tq * inv1 - mean * mean;
    float a1n  = g1[n] * rsqrtf(var + EPSV);
    float c1n  = b1[n] - mean * a1n;

    int sc = tid >> 6;
    int o  = tid & 63;
    int k4a = sc << 5;
    float a0 = 0.f, a1 = 0.f, a2 = 0.f, a3 = 0.f, wsum = 0.f;
    #pragma unroll 4
    for (int k4 = k4a; k4 < k4a + 32; k4++) {
        float4 w4 = *(const float4*)(W1T4 + (size_t)k4 * 256 + o * 4);
        float4 x0 = *(const float4*)&xs[0][k4 << 2];
        float4 x1 = *(const float4*)&xs[1][k4 << 2];
        float4 x2 = *(const float4*)&xs[2][k4 << 2];
        float4 x3 = *(const float4*)&xs[3][k4 << 2];
        wsum += w4.x + w4.y + w4.z + w4.w;
        a0 += w4.x*x0.x + w4.y*x0.y + w4.z*x0.z + w4.w*x0.w;
        a1 += w4.x*x1.x + w4.y*x1.y + w4.z*x1.z + w4.w*x1.w;
        a2 += w4.x*x2.x + w4.y*x2.y + w4.z*x2.z + w4.w*x2.w;
        a3 += w4.x*x3.x + w4.y*x3.y + w4.z*x3.z + w4.w*x3.w;
    }
    pd[sc][0][o] = a0; pd[sc][1][o] = a1; pd[sc][2][o] = a2; pd[sc][3][o] = a3;
    pw[sc][o] = wsum;
    __syncthreads();

    float y = 0.f;
    int b = tid >> 6;
    if (tid < 256) {
        float dot = 0.f, wsm = 0.f;
        #pragma unroll
        for (int ss = 0; ss < 16; ss++) { dot += pd[ss][b][o]; wsm += pw[ss][o]; }
        y = a1n * dot + c1n * wsm + bl1[o];
        float rs = y, rq = y * y;
        for (int off = 32; off; off >>= 1) {
            rs += __shfl_down(rs, off);
            rq += __shfl_down(rq, off);
        }
        if (o == 0) { sm2[b] = rs; sq2[b] = rq; }
    }
    __syncthreads();
    if (tid < 256) {
        float sm  = sm2[0] + sm2[1] + sm2[2] + sm2[3];
        float sqm = sq2[0] + sq2[1] + sq2[2] + sq2[3];
        const float inv2 = 1.f / 256.f;
        float mean2 = sm * inv2;
        float var2  = sqm * inv2 - mean2 * mean2;
        float r2s = rsqrtf(var2 + EPSV);
        out[((size_t)b * NR + n) * OO + o] = (y - mean2) * r2s * g2[n] + b2[n];
    }
}

extern "C" void kernel_launch(void* const* d_in, const int* in_sizes, int n_in,
                              void* d_out, int out_size, void* d_ws, size_t ws_size,
                              hipStream_t stream) {
    const float* feat = (const float*)d_in[0];
    const float* rois = (const float*)d_in[1];
    const float* g1   = (const float*)d_in[2];
    const float* b1   = (const float*)d_in[3];
    const float* W1   = (const float*)d_in[4];
    const float* bl1  = (const float*)d_in[5];
    const float* g2   = (const float*)d_in[6];
    const float* b2   = (const float*)d_in[7];
    float* out = (float*)d_out;

    float*  W1T4   = (float*)d_ws;                            //   524,288 B
    ushort* colmax = (ushort*)((char*)d_ws + 524288);         // 70,778,880 B

    k_colmax<<<320, 512, 0, stream>>>(feat, rois, W1, colmax, W1T4);
    k_gemm<<<NR, 1024, 0, stream>>>(colmax, rois, W1T4, bl1, g1, b1, g2, b2, out);
}